// Round 1
// baseline (21.459 us; speedup 1.0000x reference)
//
#include <hip/hip_runtime.h>

#define GB 64
#define GN 128
#define F_OBS 64
#define F_TOT 80
#define ISPLIT 16
#define IPB (GN / ISPLIT)   // 8 i-rows per block

// Block = 128 threads (2 waves), thread t = output column j.
// Block (b, is..is+7): computes A[b, i, j] for i in tile, all j, plus a
// deterministic partial of the off-diagonal log-likelihood sum.
__global__ __launch_bounds__(128) void glcn_main(
    const float* __restrict__ h, const float* __restrict__ w,
    float* __restrict__ Aout, float* __restrict__ part) {
  const int blk = blockIdx.x;
  const int b  = blk >> 4;                 // / ISPLIT
  const int is = (blk & (ISPLIT - 1)) * IPB;
  const int j  = threadIdx.x;              // 0..127

  // Own row h[b, j, 0:64] -> 64 VGPRs (vectorized, 16B loads; row stride
  // 80 floats = 320B keeps float4 alignment).
  float hj[F_OBS];
  const float* rowj = h + ((size_t)(b * GN + j)) * F_TOT;
#pragma unroll
  for (int q = 0; q < F_OBS / 4; ++q) {
    float4 v = *reinterpret_cast<const float4*>(rowj + q * 4);
    hj[q * 4 + 0] = v.x; hj[q * 4 + 1] = v.y;
    hj[q * 4 + 2] = v.z; hj[q * 4 + 3] = v.w;
  }

  float logsum = 0.f;
#pragma unroll
  for (int ii = 0; ii < IPB; ++ii) {
    const int i = is + ii;
    // h[b,i,k] and w[k] are wave-uniform -> scalar loads (s_load), so the
    // inner loop is v_sub + v_fma(abs(diff), s_w, acc): 2 VALU/MAC, no LDS.
    const float* rowi = h + ((size_t)(b * GN + i)) * F_TOT;
    float acc = 0.f;
#pragma unroll
    for (int k = 0; k < F_OBS; ++k) {
      acc = fmaf(w[k], fabsf(hj[k] - rowi[k]), acc);
    }
    // gumbel_sigmoid, rollout: y_soft = sigmoid(logit), hard threshold 0.5
    const float ysoft = 1.f / (1.f + __expf(-acc));
    float Aval = (ysoft > 0.5f) ? 1.f : 0.f;
    const float sel = (Aval != 0.f) ? ysoft : (1.f - ysoft);
    const float lt = __logf(sel + 1e-8f);
    if (i == j) {
      Aval = 1.f;            // diagonal forced to 1, excluded from log-sum
    } else {
      logsum += lt;
    }
    Aout[((size_t)(b * GN + i)) * GN + j] = Aval;   // lanes=j: coalesced
  }

  // Deterministic block reduction of logsum (fixed shuffle order).
#pragma unroll
  for (int off = 32; off > 0; off >>= 1)
    logsum += __shfl_down(logsum, off, 64);
  __shared__ float red[2];
  const int lane = threadIdx.x & 63;
  const int wid  = threadIdx.x >> 6;
  if (lane == 0) red[wid] = logsum;
  __syncthreads();
  if (threadIdx.x == 0) part[blk] = red[0] + red[1];
}

// probs[b] = sum of the 16 block partials, fixed order (deterministic).
__global__ __launch_bounds__(64) void glcn_reduce(
    const float* __restrict__ part, float* __restrict__ probs) {
  const int b = threadIdx.x;
  float s = 0.f;
#pragma unroll
  for (int q = 0; q < ISPLIT; ++q) s += part[b * ISPLIT + q];
  probs[b] = s;
}

extern "C" void kernel_launch(void* const* d_in, const int* in_sizes, int n_in,
                              void* d_out, int out_size, void* d_ws, size_t ws_size,
                              hipStream_t stream) {
  const float* h = (const float*)d_in[0];   // [64,128,80] f32
  const float* w = (const float*)d_in[1];   // [64,1] f32
  // d_in[2] = rollout (int, always 1 on this path) -- unused.
  float* Aout  = (float*)d_out;                       // [64,128,128]
  float* probs = Aout + (size_t)GB * GN * GN;         // [64]
  float* part  = (float*)d_ws;                        // 1024 floats scratch

  glcn_main<<<GB * ISPLIT, 128, 0, stream>>>(h, w, Aout, part);
  glcn_reduce<<<1, 64, 0, stream>>>(part, probs);
}